// Round 1
// baseline (1744.453 us; speedup 1.0000x reference)
//
#include <hip/hip_runtime.h>
#include <math.h>

// Problem constants (from reference)
#define N_NODES 50000
#define N_EDGES 800000
#define O_DIM   64
#define IN_DIM  192      // 2*O + ED
#define OUT_DIM 128      // 2*O
#define BN_EPS  1e-5f

// Workspace layout (float offsets):
//   P1     [N,128]  @ 0          (n_feat @ W[:,0:64]^T)
//   P2     [N,128]  @ 6,400,000  (n_feat @ W[:,64:128]^T)
//   agg    [N,64]   @ 12,800,000
//   stats1 [256]    @ 16,000,000 (sum[128], sumsq[128])
//   ss1    [256]    @ +256       (scale[128], shift[128])
//   stats2 [128]    @ +512       (sum[64], sumsq[64])
//   ss2    [128]    @ +640
// Total: 16,000,768 floats = 64.0 MB
#define OFF_P2     6400000
#define OFF_AGG    12800000
#define OFF_STATS1 16000000

#define EPW 16   // edges per wave per block-iteration
#define EPB 64   // edges per block per iteration (4 waves)

// ---------------------------------------------------------------------------
// Kernel 1: P1[n][o] = sum_k n_feat[n][k]*W[o][k]; P2 with W[o][64+k].
// W slice held in registers per thread (64 f32); 4 rows staged per iter.
__global__ __launch_bounds__(256) void k_precompute(
    const float* __restrict__ n_feat, const float* __restrict__ W,
    float* __restrict__ P1, float* __restrict__ P2) {
  const int tid  = threadIdx.x;
  const int o    = tid & 127;
  const int half = tid >> 7;          // 0 -> P1 (k 0..63), 1 -> P2 (k 64..127)
  float4 wreg[16];
  const float* wrow = W + (size_t)o * IN_DIM + half * 64;
#pragma unroll
  for (int i = 0; i < 16; ++i) wreg[i] = *(const float4*)(wrow + i * 4);
  __shared__ float xrow[4][64];
  float* __restrict__ Pdst = half ? P2 : P1;
  for (int r0 = blockIdx.x * 4; r0 < N_NODES; r0 += gridDim.x * 4) {
    {
      int r = tid >> 6, k = tid & 63;
      int rr = r0 + r;
      xrow[r][k] = (rr < N_NODES) ? n_feat[(size_t)rr * 64 + k] : 0.f;
    }
    __syncthreads();
    float acc[4] = {0.f, 0.f, 0.f, 0.f};
#pragma unroll
    for (int kk = 0; kk < 16; ++kk) {
      float4 wv = wreg[kk];
#pragma unroll
      for (int r = 0; r < 4; ++r) {
        float4 xv = *(const float4*)&xrow[r][kk * 4];  // uniform broadcast
        acc[r] += wv.x * xv.x + wv.y * xv.y + wv.z * xv.z + wv.w * xv.w;
      }
    }
#pragma unroll
    for (int r = 0; r < 4; ++r) {
      int rr = r0 + r;
      if (rr < N_NODES) Pdst[(size_t)rr * 128 + o] = acc[r];
    }
    __syncthreads();
  }
}

// ---------------------------------------------------------------------------
// Shared edge-pass machinery: wave handles EPW edges; lane l owns channels
// {l, l+64}.  Q[e][o] = sum_k e_feat[e][k]*W[o][128+k] via LDS.
// w3p[k][l] = {W[l][128+k], W[l+64][128+k]}  (float2, conflict-free b64 reads)

// Kernel 2: per-channel sum & sumsq of h over all edges (BN1 stats).
__global__ __launch_bounds__(256) void k_edge_stats(
    const float* __restrict__ e_feat, const int* __restrict__ src,
    const int* __restrict__ dst, const float* __restrict__ W,
    const float* __restrict__ b, const float* __restrict__ P1,
    const float* __restrict__ P2, float* __restrict__ stats1) {
  const int tid = threadIdx.x;
  const int l = tid & 63;
  const int w = tid >> 6;
  __shared__ float2 w3p[64 * 64];       // 32 KB
  __shared__ float  eflds[4][EPW][64];  // 16 KB
  __shared__ float  wsum[4][128];
  __shared__ float  wsq[4][128];
  for (int i = tid; i < 4096; i += 256) {
    int k = i >> 6, oo = i & 63;
    w3p[i] = make_float2(W[(size_t)oo * IN_DIM + 128 + k],
                         W[(size_t)(oo + 64) * IN_DIM + 128 + k]);
  }
  const float bias0 = b[l], bias1 = b[64 + l];
  float sum0 = 0.f, sq0 = 0.f, sum1 = 0.f, sq1 = 0.f;
  __syncthreads();
  for (int g0 = blockIdx.x * EPB; g0 < N_EDGES; g0 += gridDim.x * EPB) {
    const int e0 = g0 + w * EPW;
#pragma unroll
    for (int j = 0; j < EPW; ++j) {
      int e = e0 + j;
      eflds[w][j][l] = (e < N_EDGES) ? e_feat[(size_t)e * 64 + l] : 0.f;
    }
    __syncthreads();
    float2 q[EPW];
#pragma unroll
    for (int j = 0; j < EPW; ++j) q[j] = make_float2(0.f, 0.f);
#pragma unroll 4
    for (int kk = 0; kk < 64; kk += 4) {
      float2 wv0 = w3p[(kk + 0) * 64 + l];
      float2 wv1 = w3p[(kk + 1) * 64 + l];
      float2 wv2 = w3p[(kk + 2) * 64 + l];
      float2 wv3 = w3p[(kk + 3) * 64 + l];
#pragma unroll
      for (int j = 0; j < EPW; ++j) {
        float4 ef = *(const float4*)&eflds[w][j][kk];  // uniform b128
        q[j].x += ef.x * wv0.x + ef.y * wv1.x + ef.z * wv2.x + ef.w * wv3.x;
        q[j].y += ef.x * wv0.y + ef.y * wv1.y + ef.z * wv2.y + ef.w * wv3.y;
      }
    }
#pragma unroll
    for (int j = 0; j < EPW; ++j) {
      int e = e0 + j;
      if (e < N_EDGES) {
        int d = __builtin_amdgcn_readfirstlane(dst[e]);
        int s = __builtin_amdgcn_readfirstlane(src[e]);
        float h0 = P1[(size_t)d * 128 + l]      + P2[(size_t)s * 128 + l]      + q[j].x + bias0;
        float h1 = P1[(size_t)d * 128 + 64 + l] + P2[(size_t)s * 128 + 64 + l] + q[j].y + bias1;
        sum0 += h0; sq0 += h0 * h0;
        sum1 += h1; sq1 += h1 * h1;
      }
    }
    __syncthreads();
  }
  wsum[w][l] = sum0; wsum[w][64 + l] = sum1;
  wsq[w][l]  = sq0;  wsq[w][64 + l]  = sq1;
  __syncthreads();
  if (tid < 128) {
    float v = wsum[0][tid] + wsum[1][tid] + wsum[2][tid] + wsum[3][tid];
    unsafeAtomicAdd(&stats1[tid], v);
  } else {
    int t = tid - 128;
    float v = wsq[0][t] + wsq[1][t] + wsq[2][t] + wsq[3][t];
    unsafeAtomicAdd(&stats1[128 + t], v);
  }
}

// Kernel 3: fold BN1 into per-channel affine: scale = g1*rsqrt(var+eps),
// shift = beta1 - mu*scale.
__global__ void k_finalize1(const float* __restrict__ stats1,
                            const float* __restrict__ g1,
                            const float* __restrict__ beta1,
                            float* __restrict__ ss1) {
  int t = threadIdx.x;
  if (t < 128) {
    float inv_n = 1.f / (float)N_EDGES;
    float mu  = stats1[t] * inv_n;
    float var = stats1[128 + t] * inv_n - mu * mu;
    float sc  = g1[t] * rsqrtf(var + BN_EPS);
    ss1[t] = sc;
    ss1[128 + t] = beta1[t] - mu * sc;
  }
}

// Kernel 4: recompute h, apply BN1 affine, msg = sigmoid(filt)*softplus(core),
// scatter-add into agg[dst].
__global__ __launch_bounds__(256) void k_edge_msg(
    const float* __restrict__ e_feat, const int* __restrict__ src,
    const int* __restrict__ dst, const float* __restrict__ W,
    const float* __restrict__ b, const float* __restrict__ P1,
    const float* __restrict__ P2, const float* __restrict__ ss1,
    float* __restrict__ agg) {
  const int tid = threadIdx.x;
  const int l = tid & 63;
  const int w = tid >> 6;
  __shared__ float2 w3p[64 * 64];
  __shared__ float  eflds[4][EPW][64];
  for (int i = tid; i < 4096; i += 256) {
    int k = i >> 6, oo = i & 63;
    w3p[i] = make_float2(W[(size_t)oo * IN_DIM + 128 + k],
                         W[(size_t)(oo + 64) * IN_DIM + 128 + k]);
  }
  const float bias0 = b[l], bias1 = b[64 + l];
  const float scl0 = ss1[l], scl1 = ss1[64 + l];
  const float sft0 = ss1[128 + l], sft1 = ss1[192 + l];
  __syncthreads();
  for (int g0 = blockIdx.x * EPB; g0 < N_EDGES; g0 += gridDim.x * EPB) {
    const int e0 = g0 + w * EPW;
#pragma unroll
    for (int j = 0; j < EPW; ++j) {
      int e = e0 + j;
      eflds[w][j][l] = (e < N_EDGES) ? e_feat[(size_t)e * 64 + l] : 0.f;
    }
    __syncthreads();
    float2 q[EPW];
#pragma unroll
    for (int j = 0; j < EPW; ++j) q[j] = make_float2(0.f, 0.f);
#pragma unroll 4
    for (int kk = 0; kk < 64; kk += 4) {
      float2 wv0 = w3p[(kk + 0) * 64 + l];
      float2 wv1 = w3p[(kk + 1) * 64 + l];
      float2 wv2 = w3p[(kk + 2) * 64 + l];
      float2 wv3 = w3p[(kk + 3) * 64 + l];
#pragma unroll
      for (int j = 0; j < EPW; ++j) {
        float4 ef = *(const float4*)&eflds[w][j][kk];
        q[j].x += ef.x * wv0.x + ef.y * wv1.x + ef.z * wv2.x + ef.w * wv3.x;
        q[j].y += ef.x * wv0.y + ef.y * wv1.y + ef.z * wv2.y + ef.w * wv3.y;
      }
    }
#pragma unroll
    for (int j = 0; j < EPW; ++j) {
      int e = e0 + j;
      if (e < N_EDGES) {
        int d = __builtin_amdgcn_readfirstlane(dst[e]);
        int s = __builtin_amdgcn_readfirstlane(src[e]);
        float h0 = P1[(size_t)d * 128 + l]      + P2[(size_t)s * 128 + l]      + q[j].x + bias0;
        float h1 = P1[(size_t)d * 128 + 64 + l] + P2[(size_t)s * 128 + 64 + l] + q[j].y + bias1;
        h0 = h0 * scl0 + sft0;                        // BN1 affine (filt, chan l)
        h1 = h1 * scl1 + sft1;                        // BN1 affine (core, chan l+64)
        float sig = 1.f / (1.f + expf(-h0));
        float sp  = fmaxf(h1, 0.f) + log1pf(expf(-fabsf(h1)));  // stable softplus
        unsafeAtomicAdd(&agg[(size_t)d * 64 + l], sig * sp);
      }
    }
    __syncthreads();
  }
}

// Kernel 5: BN2 stats over agg rows.
__global__ __launch_bounds__(256) void k_agg_stats(const float* __restrict__ agg,
                                                   float* __restrict__ stats2) {
  const int tid = threadIdx.x;
  const int c = tid & 63, w = tid >> 6;
  float s = 0.f, sq = 0.f;
  for (int r = blockIdx.x * 4 + w; r < N_NODES; r += gridDim.x * 4) {
    float v = agg[(size_t)r * 64 + c];
    s += v; sq += v * v;
  }
  __shared__ float ws_[4][64], wq_[4][64];
  ws_[w][c] = s; wq_[w][c] = sq;
  __syncthreads();
  if (tid < 64) {
    unsafeAtomicAdd(&stats2[tid], ws_[0][tid] + ws_[1][tid] + ws_[2][tid] + ws_[3][tid]);
  } else if (tid < 128) {
    int t = tid - 64;
    unsafeAtomicAdd(&stats2[64 + t], wq_[0][t] + wq_[1][t] + wq_[2][t] + wq_[3][t]);
  }
}

__global__ void k_finalize2(const float* __restrict__ stats2,
                            const float* __restrict__ g2,
                            const float* __restrict__ beta2,
                            float* __restrict__ ss2) {
  int t = threadIdx.x;
  if (t < 64) {
    float inv_n = 1.f / (float)N_NODES;
    float mu  = stats2[t] * inv_n;
    float var = stats2[64 + t] * inv_n - mu * mu;
    float sc  = g2[t] * rsqrtf(var + BN_EPS);
    ss2[t] = sc;
    ss2[64 + t] = beta2[t] - mu * sc;
  }
}

// Kernel 7: out = softplus(BN2(agg) + n_feat), float4-vectorized.
__global__ __launch_bounds__(256) void k_output(const float* __restrict__ agg,
                                                const float* __restrict__ n_feat,
                                                const float* __restrict__ ss2,
                                                float* __restrict__ out) {
  int i = blockIdx.x * 256 + threadIdx.x;       // float4 index
  if (i >= N_NODES * 16) return;
  int cb = (i & 15) * 4;                        // channel base (64 | row)
  float4 a = ((const float4*)agg)[i];
  float4 x = ((const float4*)n_feat)[i];
  float4 r;
  {
    float v = a.x * ss2[cb + 0] + ss2[64 + cb + 0] + x.x;
    r.x = fmaxf(v, 0.f) + log1pf(expf(-fabsf(v)));
  }
  {
    float v = a.y * ss2[cb + 1] + ss2[64 + cb + 1] + x.y;
    r.y = fmaxf(v, 0.f) + log1pf(expf(-fabsf(v)));
  }
  {
    float v = a.z * ss2[cb + 2] + ss2[64 + cb + 2] + x.z;
    r.z = fmaxf(v, 0.f) + log1pf(expf(-fabsf(v)));
  }
  {
    float v = a.w * ss2[cb + 3] + ss2[64 + cb + 3] + x.w;
    r.w = fmaxf(v, 0.f) + log1pf(expf(-fabsf(v)));
  }
  ((float4*)out)[i] = r;
}

extern "C" void kernel_launch(void* const* d_in, const int* in_sizes, int n_in,
                              void* d_out, int out_size, void* d_ws, size_t ws_size,
                              hipStream_t stream) {
  const float* n_feat = (const float*)d_in[0];
  const float* e_feat = (const float*)d_in[1];
  const int*   src    = (const int*)d_in[2];
  const int*   dst    = (const int*)d_in[3];
  const float* W      = (const float*)d_in[4];
  const float* b      = (const float*)d_in[5];
  const float* g1     = (const float*)d_in[6];
  const float* beta1  = (const float*)d_in[7];
  const float* g2     = (const float*)d_in[8];
  const float* beta2  = (const float*)d_in[9];

  float* ws     = (float*)d_ws;
  float* P1     = ws;
  float* P2     = ws + OFF_P2;
  float* agg    = ws + OFF_AGG;
  float* stats1 = ws + OFF_STATS1;
  float* ss1    = stats1 + 256;
  float* stats2 = ss1 + 256;
  float* ss2    = stats2 + 128;
  float* out    = (float*)d_out;

  // zero accumulators (ws is poisoned 0xAA before every call)
  hipMemsetAsync(agg, 0, (size_t)N_NODES * 64 * sizeof(float), stream);
  hipMemsetAsync(stats1, 0, (256 + 256 + 128 + 128) * sizeof(float), stream);

  k_precompute<<<1024, 256, 0, stream>>>(n_feat, W, P1, P2);
  k_edge_stats<<<1024, 256, 0, stream>>>(e_feat, src, dst, W, b, P1, P2, stats1);
  k_finalize1<<<1, 128, 0, stream>>>(stats1, g1, beta1, ss1);
  k_edge_msg<<<1024, 256, 0, stream>>>(e_feat, src, dst, W, b, P1, P2, ss1, agg);
  k_agg_stats<<<512, 256, 0, stream>>>(agg, stats2);
  k_finalize2<<<1, 64, 0, stream>>>(stats2, g2, beta2, ss2);
  k_output<<<3125, 256, 0, stream>>>(agg, n_feat, ss2, out);
}

// Round 2
// 993.006 us; speedup vs baseline: 1.7567x; 1.7567x over previous
//
#include <hip/hip_runtime.h>
#include <math.h>

// Problem constants (from reference)
#define N_NODES 50000
#define N_EDGES 800000
#define IN_DIM  192      // 2*O + ED
#define BN_EPS  1e-5f

// Workspace layout (float offsets):
//   P1     [N,128]  @ 0          (n_feat @ W[:,0:64]^T)
//   P2     [N,128]  @ 6,400,000  (n_feat @ W[:,64:128]^T)
//   agg    [N,64]   @ 12,800,000
//   stats1 [256]    @ 16,000,000 (sum[128], sumsq[128])
//   ss1    [256]    @ +256       (scale[128], shift[128])
//   stats2 [128]    @ +512
//   ss2    [128]    @ +640
#define OFF_P2     6400000
#define OFF_AGG    12800000
#define OFF_STATS1 16000000

typedef __bf16 bf16x8 __attribute__((ext_vector_type(8)));
typedef float  f32x4  __attribute__((ext_vector_type(4)));

// ---------------------------------------------------------------------------
// Kernel 1: P1[n][o] = sum_k n_feat[n][k]*W[o][k]; P2 with W[o][64+k]. (f32)
__global__ __launch_bounds__(256) void k_precompute(
    const float* __restrict__ n_feat, const float* __restrict__ W,
    float* __restrict__ P1, float* __restrict__ P2) {
  const int tid  = threadIdx.x;
  const int o    = tid & 127;
  const int half = tid >> 7;
  float4 wreg[16];
  const float* wrow = W + (size_t)o * IN_DIM + half * 64;
#pragma unroll
  for (int i = 0; i < 16; ++i) wreg[i] = *(const float4*)(wrow + i * 4);
  __shared__ float xrow[4][64];
  float* __restrict__ Pdst = half ? P2 : P1;
  for (int r0 = blockIdx.x * 4; r0 < N_NODES; r0 += gridDim.x * 4) {
    {
      int r = tid >> 6, k = tid & 63;
      int rr = r0 + r;
      xrow[r][k] = (rr < N_NODES) ? n_feat[(size_t)rr * 64 + k] : 0.f;
    }
    __syncthreads();
    float acc[4] = {0.f, 0.f, 0.f, 0.f};
#pragma unroll
    for (int kk = 0; kk < 16; ++kk) {
      float4 wv = wreg[kk];
#pragma unroll
      for (int r = 0; r < 4; ++r) {
        float4 xv = *(const float4*)&xrow[r][kk * 4];
        acc[r] += wv.x * xv.x + wv.y * xv.y + wv.z * xv.z + wv.w * xv.w;
      }
    }
#pragma unroll
    for (int r = 0; r < 4; ++r) {
      int rr = r0 + r;
      if (rr < N_NODES) Pdst[(size_t)rr * 128 + o] = acc[r];
    }
    __syncthreads();
  }
}

// ---------------------------------------------------------------------------
// MFMA edge-pass core.  Wave computes h[16 edges][128 ch] for group base e0.
//   Q = e_feat_tile(bf16) @ W3^T(bf16) via 16x16x32 MFMA, f32 accumulate.
//   A-frag: lane holds A[m=lane&15][k=(lane>>4)*8+j]  -> e_feat row e0+(l&15)
//   B-frag: lane holds B[k=(lane>>4)*8+j][n=lane&15]  -> W3 row nt*16+(l&15)
//   D-frag: lane holds D[m=(lane>>4)*4+r][n=nt*16+(lane&15)]
// Then h = Q + P1[dst] + P2[src] + b  (all f32 gathers, quad-contiguous 64B).
__device__ __forceinline__ void load_W3_frags(const float* __restrict__ W,
                                              int lane, bf16x8* Bf) {
  const int c = lane & 15, q = lane >> 4;
#pragma unroll
  for (int nt = 0; nt < 8; ++nt) {
#pragma unroll
    for (int ks = 0; ks < 2; ++ks) {
      const float* wr = W + (size_t)(nt * 16 + c) * IN_DIM + 128 + ks * 32 + q * 8;
      f32x4 w0 = *(const f32x4*)wr;
      f32x4 w1 = *(const f32x4*)(wr + 4);
      bf16x8 f;
#pragma unroll
      for (int j = 0; j < 4; ++j) { f[j] = (__bf16)w0[j]; f[4 + j] = (__bf16)w1[j]; }
      Bf[nt * 2 + ks] = f;
    }
  }
}

__device__ __forceinline__ void compute_h(
    int e0, int lane, const float* __restrict__ e_feat,
    const int* __restrict__ src, const int* __restrict__ dst,
    const float* __restrict__ P1, const float* __restrict__ P2,
    const float* __restrict__ bn_, const bf16x8* Bf,
    float h[8][4], int dIdx[4]) {
  const int c = lane & 15, q = lane >> 4;
  // A fragments: direct global loads (wave covers 16 full contiguous rows)
  const float* er = e_feat + (size_t)(e0 + c) * 64 + q * 8;
  f32x4 a0 = *(const f32x4*)er;
  f32x4 a1 = *(const f32x4*)(er + 4);
  f32x4 a2 = *(const f32x4*)(er + 32);
  f32x4 a3 = *(const f32x4*)(er + 36);
  int sIdx[4];
#pragma unroll
  for (int r = 0; r < 4; ++r) {          // D rows owned by this lane's quad
    dIdx[r] = dst[e0 + q * 4 + r];
    sIdx[r] = src[e0 + q * 4 + r];
  }
  bf16x8 A0, A1;
#pragma unroll
  for (int j = 0; j < 4; ++j) {
    A0[j] = (__bf16)a0[j]; A0[4 + j] = (__bf16)a1[j];
    A1[j] = (__bf16)a2[j]; A1[4 + j] = (__bf16)a3[j];
  }
  f32x4 acc[8];
#pragma unroll
  for (int nt = 0; nt < 8; ++nt) {
    acc[nt] = (f32x4){0.f, 0.f, 0.f, 0.f};
    acc[nt] = __builtin_amdgcn_mfma_f32_16x16x32_bf16(A0, Bf[nt * 2 + 0], acc[nt], 0, 0, 0);
    acc[nt] = __builtin_amdgcn_mfma_f32_16x16x32_bf16(A1, Bf[nt * 2 + 1], acc[nt], 0, 0, 0);
  }
#pragma unroll
  for (int nt = 0; nt < 8; ++nt) {
    const int n = nt * 16 + c;
#pragma unroll
    for (int r = 0; r < 4; ++r) {
      h[nt][r] = acc[nt][r] + P1[dIdx[r] * 128 + n] + P2[sIdx[r] * 128 + n] + bn_[nt];
    }
  }
}

// ---------------------------------------------------------------------------
// Kernel 2: BN1 stats (per-channel sum & sumsq of h over all edges).
__global__ __launch_bounds__(256, 3) void k_edge_stats(
    const float* __restrict__ e_feat, const int* __restrict__ src,
    const int* __restrict__ dst, const float* __restrict__ W,
    const float* __restrict__ b, const float* __restrict__ P1,
    const float* __restrict__ P2, float* __restrict__ stats1) {
  const int tid = threadIdx.x, lane = tid & 63, w = tid >> 6;
  const int c = lane & 15;
  bf16x8 Bf[16];
  load_W3_frags(W, lane, Bf);
  float bn_[8];
#pragma unroll
  for (int nt = 0; nt < 8; ++nt) bn_[nt] = b[nt * 16 + c];
  float sums[8] = {0, 0, 0, 0, 0, 0, 0, 0};
  float sqs[8]  = {0, 0, 0, 0, 0, 0, 0, 0};
  for (int g0 = blockIdx.x * 64; g0 < N_EDGES; g0 += gridDim.x * 64) {
    const int e0 = g0 + w * 16;
    float h[8][4]; int dIdx[4];
    compute_h(e0, lane, e_feat, src, dst, P1, P2, bn_, Bf, h, dIdx);
#pragma unroll
    for (int nt = 0; nt < 8; ++nt)
#pragma unroll
      for (int r = 0; r < 4; ++r) {
        sums[nt] += h[nt][r];
        sqs[nt]  += h[nt][r] * h[nt][r];
      }
  }
  // reduce the 4 quads (different edge-rows, same channel) then cross-wave
  __shared__ float red[4][256];
#pragma unroll
  for (int nt = 0; nt < 8; ++nt) {
    float s = sums[nt]; s += __shfl_xor(s, 16, 64); s += __shfl_xor(s, 32, 64);
    float qv = sqs[nt]; qv += __shfl_xor(qv, 16, 64); qv += __shfl_xor(qv, 32, 64);
    if (lane < 16) { red[w][nt * 16 + lane] = s; red[w][128 + nt * 16 + lane] = qv; }
  }
  __syncthreads();
  float v = red[0][tid] + red[1][tid] + red[2][tid] + red[3][tid];
  unsafeAtomicAdd(&stats1[tid], v);
}

// Kernel 3: fold BN1 into per-channel affine.
__global__ void k_finalize1(const float* __restrict__ stats1,
                            const float* __restrict__ g1,
                            const float* __restrict__ beta1,
                            float* __restrict__ ss1) {
  int t = threadIdx.x;
  if (t < 128) {
    float inv_n = 1.f / (float)N_EDGES;
    float mu  = stats1[t] * inv_n;
    float var = stats1[128 + t] * inv_n - mu * mu;
    float sc  = g1[t] * rsqrtf(var + BN_EPS);
    ss1[t] = sc;
    ss1[128 + t] = beta1[t] - mu * sc;
  }
}

// Kernel 4: recompute h, BN1 affine, msg = sigmoid(filt)*softplus(core),
// scatter-add into agg[dst].  filt chan n, core chan n+64 -> frags nt, nt+4.
__global__ __launch_bounds__(256, 3) void k_edge_msg(
    const float* __restrict__ e_feat, const int* __restrict__ src,
    const int* __restrict__ dst, const float* __restrict__ W,
    const float* __restrict__ b, const float* __restrict__ P1,
    const float* __restrict__ P2, const float* __restrict__ ss1,
    float* __restrict__ agg) {
  const int tid = threadIdx.x, lane = tid & 63, w = tid >> 6;
  const int c = lane & 15;
  bf16x8 Bf[16];
  load_W3_frags(W, lane, Bf);
  float bn_[8], sc[8], sh[8];
#pragma unroll
  for (int nt = 0; nt < 8; ++nt) {
    bn_[nt] = b[nt * 16 + c];
    sc[nt]  = ss1[nt * 16 + c];
    sh[nt]  = ss1[128 + nt * 16 + c];
  }
  for (int g0 = blockIdx.x * 64; g0 < N_EDGES; g0 += gridDim.x * 64) {
    const int e0 = g0 + w * 16;
    float h[8][4]; int dIdx[4];
    compute_h(e0, lane, e_feat, src, dst, P1, P2, bn_, Bf, h, dIdx);
#pragma unroll
    for (int nt = 0; nt < 4; ++nt) {
#pragma unroll
      for (int r = 0; r < 4; ++r) {
        float f = h[nt][r] * sc[nt] + sh[nt];                  // filt, chan nt*16+c
        float g = h[nt + 4][r] * sc[nt + 4] + sh[nt + 4];      // core, chan +64
        float sig = 1.f / (1.f + expf(-f));
        float sp  = fmaxf(g, 0.f) + log1pf(expf(-fabsf(g)));   // stable softplus
        unsafeAtomicAdd(&agg[(size_t)dIdx[r] * 64 + nt * 16 + c], sig * sp);
      }
    }
  }
}

// Kernel 5: BN2 stats over agg rows.
__global__ __launch_bounds__(256) void k_agg_stats(const float* __restrict__ agg,
                                                   float* __restrict__ stats2) {
  const int tid = threadIdx.x;
  const int c = tid & 63, w = tid >> 6;
  float s = 0.f, sq = 0.f;
  for (int r = blockIdx.x * 4 + w; r < N_NODES; r += gridDim.x * 4) {
    float v = agg[(size_t)r * 64 + c];
    s += v; sq += v * v;
  }
  __shared__ float ws_[4][64], wq_[4][64];
  ws_[w][c] = s; wq_[w][c] = sq;
  __syncthreads();
  if (tid < 64) {
    unsafeAtomicAdd(&stats2[tid], ws_[0][tid] + ws_[1][tid] + ws_[2][tid] + ws_[3][tid]);
  } else if (tid < 128) {
    int t = tid - 64;
    unsafeAtomicAdd(&stats2[64 + t], wq_[0][t] + wq_[1][t] + wq_[2][t] + wq_[3][t]);
  }
}

__global__ void k_finalize2(const float* __restrict__ stats2,
                            const float* __restrict__ g2,
                            const float* __restrict__ beta2,
                            float* __restrict__ ss2) {
  int t = threadIdx.x;
  if (t < 64) {
    float inv_n = 1.f / (float)N_NODES;
    float mu  = stats2[t] * inv_n;
    float var = stats2[64 + t] * inv_n - mu * mu;
    float sc  = g2[t] * rsqrtf(var + BN_EPS);
    ss2[t] = sc;
    ss2[64 + t] = beta2[t] - mu * sc;
  }
}

// Kernel 7: out = softplus(BN2(agg) + n_feat), float4-vectorized.
__global__ __launch_bounds__(256) void k_output(const float* __restrict__ agg,
                                                const float* __restrict__ n_feat,
                                                const float* __restrict__ ss2,
                                                float* __restrict__ out) {
  int i = blockIdx.x * 256 + threadIdx.x;
  if (i >= N_NODES * 16) return;
  int cb = (i & 15) * 4;
  float4 a = ((const float4*)agg)[i];
  float4 x = ((const float4*)n_feat)[i];
  float4 r;
  {
    float v = a.x * ss2[cb + 0] + ss2[64 + cb + 0] + x.x;
    r.x = fmaxf(v, 0.f) + log1pf(expf(-fabsf(v)));
  }
  {
    float v = a.y * ss2[cb + 1] + ss2[64 + cb + 1] + x.y;
    r.y = fmaxf(v, 0.f) + log1pf(expf(-fabsf(v)));
  }
  {
    float v = a.z * ss2[cb + 2] + ss2[64 + cb + 2] + x.z;
    r.z = fmaxf(v, 0.f) + log1pf(expf(-fabsf(v)));
  }
  {
    float v = a.w * ss2[cb + 3] + ss2[64 + cb + 3] + x.w;
    r.w = fmaxf(v, 0.f) + log1pf(expf(-fabsf(v)));
  }
  ((float4*)out)[i] = r;
}

extern "C" void kernel_launch(void* const* d_in, const int* in_sizes, int n_in,
                              void* d_out, int out_size, void* d_ws, size_t ws_size,
                              hipStream_t stream) {
  const float* n_feat = (const float*)d_in[0];
  const float* e_feat = (const float*)d_in[1];
  const int*   src    = (const int*)d_in[2];
  const int*   dst    = (const int*)d_in[3];
  const float* W      = (const float*)d_in[4];
  const float* b      = (const float*)d_in[5];
  const float* g1     = (const float*)d_in[6];
  const float* beta1  = (const float*)d_in[7];
  const float* g2     = (const float*)d_in[8];
  const float* beta2  = (const float*)d_in[9];

  float* ws     = (float*)d_ws;
  float* P1     = ws;
  float* P2     = ws + OFF_P2;
  float* agg    = ws + OFF_AGG;
  float* stats1 = ws + OFF_STATS1;
  float* ss1    = stats1 + 256;
  float* stats2 = ss1 + 256;
  float* ss2    = stats2 + 128;
  float* out    = (float*)d_out;

  hipMemsetAsync(agg, 0, (size_t)N_NODES * 64 * sizeof(float), stream);
  hipMemsetAsync(stats1, 0, (256 + 256 + 128 + 128) * sizeof(float), stream);

  k_precompute<<<1024, 256, 0, stream>>>(n_feat, W, P1, P2);
  k_edge_stats<<<2048, 256, 0, stream>>>(e_feat, src, dst, W, b, P1, P2, stats1);
  k_finalize1<<<1, 128, 0, stream>>>(stats1, g1, beta1, ss1);
  k_edge_msg<<<2048, 256, 0, stream>>>(e_feat, src, dst, W, b, P1, P2, ss1, agg);
  k_agg_stats<<<512, 256, 0, stream>>>(agg, stats2);
  k_finalize2<<<1, 64, 0, stream>>>(stats2, g2, beta2, ss2);
  k_output<<<3125, 256, 0, stream>>>(agg, n_feat, ss2, out);
}

// Round 3
// 784.031 us; speedup vs baseline: 2.2250x; 1.2665x over previous
//
#include <hip/hip_runtime.h>
#include <math.h>

// Problem constants (from reference)
#define N_NODES 50000
#define N_EDGES 800000
#define IN_DIM  192      // 2*O + ED
#define BN_EPS  1e-5f

// Workspace layout (float offsets):
//   P1     [N,128]  @ 0          (n_feat @ W[:,0:64]^T)
//   P2     [N,128]  @ 6,400,000  (n_feat @ W[:,64:128]^T)
//   agg    [N,64]   @ 12,800,000
//   stats1 [256]    @ 16,000,000 (sum[128], sumsq[128])
//   ss1    [256]    @ +256       (scale[128], shift[128])
//   stats2 [128]    @ +512
//   ss2    [128]    @ +640
//   hbuf   [E,64]   @ 16,001,024 (uint: packed bf16x2 {filt,core} per chan)
#define OFF_P2     6400000
#define OFF_AGG    12800000
#define OFF_STATS1 16000000
#define OFF_HBUF   16001024
#define WS_FLOATS_NEEDED (OFF_HBUF + (size_t)N_EDGES * 64)

typedef __bf16 bf16x8 __attribute__((ext_vector_type(8)));
typedef __bf16 bf16x2 __attribute__((ext_vector_type(2)));
typedef float  f32x4  __attribute__((ext_vector_type(4)));

// ---------------------------------------------------------------------------
// Kernel 1: P1[n][o] = sum_k n_feat[n][k]*W[o][k]; P2 with W[o][64+k]. (f32)
__global__ __launch_bounds__(256) void k_precompute(
    const float* __restrict__ n_feat, const float* __restrict__ W,
    float* __restrict__ P1, float* __restrict__ P2) {
  const int tid  = threadIdx.x;
  const int o    = tid & 127;
  const int half = tid >> 7;
  float4 wreg[16];
  const float* wrow = W + (size_t)o * IN_DIM + half * 64;
#pragma unroll
  for (int i = 0; i < 16; ++i) wreg[i] = *(const float4*)(wrow + i * 4);
  __shared__ float xrow[4][64];
  float* __restrict__ Pdst = half ? P2 : P1;
  for (int r0 = blockIdx.x * 4; r0 < N_NODES; r0 += gridDim.x * 4) {
    {
      int r = tid >> 6, k = tid & 63;
      int rr = r0 + r;
      xrow[r][k] = (rr < N_NODES) ? n_feat[(size_t)rr * 64 + k] : 0.f;
    }
    __syncthreads();
    float acc[4] = {0.f, 0.f, 0.f, 0.f};
#pragma unroll
    for (int kk = 0; kk < 16; ++kk) {
      float4 wv = wreg[kk];
#pragma unroll
      for (int r = 0; r < 4; ++r) {
        float4 xv = *(const float4*)&xrow[r][kk * 4];
        acc[r] += wv.x * xv.x + wv.y * xv.y + wv.z * xv.z + wv.w * xv.w;
      }
    }
#pragma unroll
    for (int r = 0; r < 4; ++r) {
      int rr = r0 + r;
      if (rr < N_NODES) Pdst[(size_t)rr * 128 + o] = acc[r];
    }
    __syncthreads();
  }
}

// ---------------------------------------------------------------------------
// MFMA edge-pass core.  Wave computes h[16 edges][128 ch] for group base e0.
//   Q = e_feat_tile(bf16) @ W3^T(bf16) via 16x16x32 MFMA, f32 accumulate.
//   D-frag: lane holds D[m=(lane>>4)*4+r][n=nt*16+(lane&15)]
__device__ __forceinline__ void load_W3_frags(const float* __restrict__ W,
                                              int lane, bf16x8* Bf) {
  const int c = lane & 15, q = lane >> 4;
#pragma unroll
  for (int nt = 0; nt < 8; ++nt) {
#pragma unroll
    for (int ks = 0; ks < 2; ++ks) {
      const float* wr = W + (size_t)(nt * 16 + c) * IN_DIM + 128 + ks * 32 + q * 8;
      f32x4 w0 = *(const f32x4*)wr;
      f32x4 w1 = *(const f32x4*)(wr + 4);
      bf16x8 f;
#pragma unroll
      for (int j = 0; j < 4; ++j) { f[j] = (__bf16)w0[j]; f[4 + j] = (__bf16)w1[j]; }
      Bf[nt * 2 + ks] = f;
    }
  }
}

__device__ __forceinline__ void compute_h(
    int e0, int lane, const float* __restrict__ e_feat,
    const int* __restrict__ src, const int* __restrict__ dst,
    const float* __restrict__ P1, const float* __restrict__ P2,
    const float* __restrict__ bn_, const bf16x8* Bf,
    float h[8][4], int dIdx[4]) {
  const int c = lane & 15, q = lane >> 4;
  const float* er = e_feat + (size_t)(e0 + c) * 64 + q * 8;
  f32x4 a0 = __builtin_nontemporal_load((const f32x4*)er);
  f32x4 a1 = __builtin_nontemporal_load((const f32x4*)(er + 4));
  f32x4 a2 = __builtin_nontemporal_load((const f32x4*)(er + 32));
  f32x4 a3 = __builtin_nontemporal_load((const f32x4*)(er + 36));
  int sIdx[4];
#pragma unroll
  for (int r = 0; r < 4; ++r) {
    dIdx[r] = dst[e0 + q * 4 + r];
    sIdx[r] = src[e0 + q * 4 + r];
  }
  bf16x8 A0, A1;
#pragma unroll
  for (int j = 0; j < 4; ++j) {
    A0[j] = (__bf16)a0[j]; A0[4 + j] = (__bf16)a1[j];
    A1[j] = (__bf16)a2[j]; A1[4 + j] = (__bf16)a3[j];
  }
  f32x4 acc[8];
#pragma unroll
  for (int nt = 0; nt < 8; ++nt) {
    acc[nt] = (f32x4){0.f, 0.f, 0.f, 0.f};
    acc[nt] = __builtin_amdgcn_mfma_f32_16x16x32_bf16(A0, Bf[nt * 2 + 0], acc[nt], 0, 0, 0);
    acc[nt] = __builtin_amdgcn_mfma_f32_16x16x32_bf16(A1, Bf[nt * 2 + 1], acc[nt], 0, 0, 0);
  }
#pragma unroll
  for (int nt = 0; nt < 8; ++nt) {
    const int n = nt * 16 + c;
#pragma unroll
    for (int r = 0; r < 4; ++r) {
      h[nt][r] = acc[nt][r] + P1[dIdx[r] * 128 + n] + P2[sIdx[r] * 128 + n] + bn_[nt];
    }
  }
}

// ---------------------------------------------------------------------------
// Kernel 2: compute h, accumulate BN1 stats, AND materialize h as packed
// bf16x2 {filt(chan n), core(chan n+64)} at hbuf[e*64 + n]  (n in 0..63).
__global__ __launch_bounds__(256, 3) void k_edge_h(
    const float* __restrict__ e_feat, const int* __restrict__ src,
    const int* __restrict__ dst, const float* __restrict__ W,
    const float* __restrict__ b, const float* __restrict__ P1,
    const float* __restrict__ P2, float* __restrict__ stats1,
    unsigned int* __restrict__ hbuf) {
  const int tid = threadIdx.x, lane = tid & 63, w = tid >> 6;
  const int c = lane & 15, q = lane >> 4;
  bf16x8 Bf[16];
  load_W3_frags(W, lane, Bf);
  float bn_[8];
#pragma unroll
  for (int nt = 0; nt < 8; ++nt) bn_[nt] = b[nt * 16 + c];
  float sums[8] = {0, 0, 0, 0, 0, 0, 0, 0};
  float sqs[8]  = {0, 0, 0, 0, 0, 0, 0, 0};
  for (int g0 = blockIdx.x * 64; g0 < N_EDGES; g0 += gridDim.x * 64) {
    const int e0 = g0 + w * 16;
    float h[8][4]; int dIdx[4];
    compute_h(e0, lane, e_feat, src, dst, P1, P2, bn_, Bf, h, dIdx);
#pragma unroll
    for (int nt = 0; nt < 8; ++nt)
#pragma unroll
      for (int r = 0; r < 4; ++r) {
        sums[nt] += h[nt][r];
        sqs[nt]  += h[nt][r] * h[nt][r];
      }
    // store packed pairs: edge e0+q*4+r, channel nt*16+c  (nt<4)
#pragma unroll
    for (int r = 0; r < 4; ++r) {
      unsigned int* hb = hbuf + (size_t)(e0 + q * 4 + r) * 64 + c;
#pragma unroll
      for (int nt = 0; nt < 4; ++nt) {
        union { bf16x2 v; unsigned int u; } pk;
        pk.v[0] = (__bf16)h[nt][r];
        pk.v[1] = (__bf16)h[nt + 4][r];
        __builtin_nontemporal_store(pk.u, hb + nt * 16);
      }
    }
  }
  __shared__ float red[4][256];
#pragma unroll
  for (int nt = 0; nt < 8; ++nt) {
    float s = sums[nt]; s += __shfl_xor(s, 16, 64); s += __shfl_xor(s, 32, 64);
    float qv = sqs[nt]; qv += __shfl_xor(qv, 16, 64); qv += __shfl_xor(qv, 32, 64);
    if (lane < 16) { red[w][nt * 16 + lane] = s; red[w][128 + nt * 16 + lane] = qv; }
  }
  __syncthreads();
  float v = red[0][tid] + red[1][tid] + red[2][tid] + red[3][tid];
  unsafeAtomicAdd(&stats1[tid], v);
}

// Kernel 3: fold BN1 into per-channel affine.
__global__ void k_finalize1(const float* __restrict__ stats1,
                            const float* __restrict__ g1,
                            const float* __restrict__ beta1,
                            float* __restrict__ ss1) {
  int t = threadIdx.x;
  if (t < 128) {
    float inv_n = 1.f / (float)N_EDGES;
    float mu  = stats1[t] * inv_n;
    float var = stats1[128 + t] * inv_n - mu * mu;
    float sc  = g1[t] * rsqrtf(var + BN_EPS);
    ss1[t] = sc;
    ss1[128 + t] = beta1[t] - mu * sc;
  }
}

// Kernel 4 (streaming): read packed h, BN1 affine, msg=sigmoid*softplus,
// scatter into agg[dst].  Wave per edge, lane per channel; 4-edge unroll.
__global__ __launch_bounds__(256) void k_msg_scatter(
    const unsigned int* __restrict__ hbuf, const int* __restrict__ dst,
    const float* __restrict__ ss1, float* __restrict__ agg) {
  const int tid = threadIdx.x, lane = tid & 63, w = tid >> 6;
  const float sc_f = ss1[lane], sc_g = ss1[64 + lane];
  const float sh_f = ss1[128 + lane], sh_g = ss1[192 + lane];
  const int wave_id = blockIdx.x * 4 + w;
  const int n_waves = gridDim.x * 4;
  for (int e0 = wave_id * 4; e0 < N_EDGES; e0 += n_waves * 4) {
    unsigned int p[4];
    int d[4];
#pragma unroll
    for (int j = 0; j < 4; ++j) {
      p[j] = __builtin_nontemporal_load(hbuf + (size_t)(e0 + j) * 64 + lane);
      d[j] = __builtin_amdgcn_readfirstlane(dst[e0 + j]);
    }
#pragma unroll
    for (int j = 0; j < 4; ++j) {
      union { unsigned int u; bf16x2 v; } pk; pk.u = p[j];
      float f = (float)pk.v[0] * sc_f + sh_f;
      float g = (float)pk.v[1] * sc_g + sh_g;
      float sig = 1.f / (1.f + expf(-f));
      float sp  = fmaxf(g, 0.f) + log1pf(expf(-fabsf(g)));
      unsafeAtomicAdd(&agg[(size_t)d[j] * 64 + lane], sig * sp);
    }
  }
}

// Fallback pass 2 (recompute h) if ws_size is too small for hbuf.
__global__ __launch_bounds__(256, 3) void k_edge_msg(
    const float* __restrict__ e_feat, const int* __restrict__ src,
    const int* __restrict__ dst, const float* __restrict__ W,
    const float* __restrict__ b, const float* __restrict__ P1,
    const float* __restrict__ P2, const float* __restrict__ ss1,
    float* __restrict__ agg) {
  const int tid = threadIdx.x, lane = tid & 63, w = tid >> 6;
  const int c = lane & 15;
  bf16x8 Bf[16];
  load_W3_frags(W, lane, Bf);
  float bn_[8], sc[8], sh[8];
#pragma unroll
  for (int nt = 0; nt < 8; ++nt) {
    bn_[nt] = b[nt * 16 + c];
    sc[nt]  = ss1[nt * 16 + c];
    sh[nt]  = ss1[128 + nt * 16 + c];
  }
  for (int g0 = blockIdx.x * 64; g0 < N_EDGES; g0 += gridDim.x * 64) {
    const int e0 = g0 + w * 16;
    float h[8][4]; int dIdx[4];
    compute_h(e0, lane, e_feat, src, dst, P1, P2, bn_, Bf, h, dIdx);
#pragma unroll
    for (int nt = 0; nt < 4; ++nt) {
#pragma unroll
      for (int r = 0; r < 4; ++r) {
        float f = h[nt][r] * sc[nt] + sh[nt];
        float g = h[nt + 4][r] * sc[nt + 4] + sh[nt + 4];
        float sig = 1.f / (1.f + expf(-f));
        float sp  = fmaxf(g, 0.f) + log1pf(expf(-fabsf(g)));
        unsafeAtomicAdd(&agg[(size_t)dIdx[r] * 64 + nt * 16 + c], sig * sp);
      }
    }
  }
}

// Kernel 5: BN2 stats over agg rows.
__global__ __launch_bounds__(256) void k_agg_stats(const float* __restrict__ agg,
                                                   float* __restrict__ stats2) {
  const int tid = threadIdx.x;
  const int c = tid & 63, w = tid >> 6;
  float s = 0.f, sq = 0.f;
  for (int r = blockIdx.x * 4 + w; r < N_NODES; r += gridDim.x * 4) {
    float v = agg[(size_t)r * 64 + c];
    s += v; sq += v * v;
  }
  __shared__ float ws_[4][64], wq_[4][64];
  ws_[w][c] = s; wq_[w][c] = sq;
  __syncthreads();
  if (tid < 64) {
    unsafeAtomicAdd(&stats2[tid], ws_[0][tid] + ws_[1][tid] + ws_[2][tid] + ws_[3][tid]);
  } else if (tid < 128) {
    int t = tid - 64;
    unsafeAtomicAdd(&stats2[64 + t], wq_[0][t] + wq_[1][t] + wq_[2][t] + wq_[3][t]);
  }
}

__global__ void k_finalize2(const float* __restrict__ stats2,
                            const float* __restrict__ g2,
                            const float* __restrict__ beta2,
                            float* __restrict__ ss2) {
  int t = threadIdx.x;
  if (t < 64) {
    float inv_n = 1.f / (float)N_NODES;
    float mu  = stats2[t] * inv_n;
    float var = stats2[64 + t] * inv_n - mu * mu;
    float sc  = g2[t] * rsqrtf(var + BN_EPS);
    ss2[t] = sc;
    ss2[64 + t] = beta2[t] - mu * sc;
  }
}

// Kernel 7: out = softplus(BN2(agg) + n_feat), float4-vectorized.
__global__ __launch_bounds__(256) void k_output(const float* __restrict__ agg,
                                                const float* __restrict__ n_feat,
                                                const float* __restrict__ ss2,
                                                float* __restrict__ out) {
  int i = blockIdx.x * 256 + threadIdx.x;
  if (i >= N_NODES * 16) return;
  int cb = (i & 15) * 4;
  float4 a = ((const float4*)agg)[i];
  float4 x = ((const float4*)n_feat)[i];
  float4 r;
  {
    float v = a.x * ss2[cb + 0] + ss2[64 + cb + 0] + x.x;
    r.x = fmaxf(v, 0.f) + log1pf(expf(-fabsf(v)));
  }
  {
    float v = a.y * ss2[cb + 1] + ss2[64 + cb + 1] + x.y;
    r.y = fmaxf(v, 0.f) + log1pf(expf(-fabsf(v)));
  }
  {
    float v = a.z * ss2[cb + 2] + ss2[64 + cb + 2] + x.z;
    r.z = fmaxf(v, 0.f) + log1pf(expf(-fabsf(v)));
  }
  {
    float v = a.w * ss2[cb + 3] + ss2[64 + cb + 3] + x.w;
    r.w = fmaxf(v, 0.f) + log1pf(expf(-fabsf(v)));
  }
  ((float4*)out)[i] = r;
}

extern "C" void kernel_launch(void* const* d_in, const int* in_sizes, int n_in,
                              void* d_out, int out_size, void* d_ws, size_t ws_size,
                              hipStream_t stream) {
  const float* n_feat = (const float*)d_in[0];
  const float* e_feat = (const float*)d_in[1];
  const int*   src    = (const int*)d_in[2];
  const int*   dst    = (const int*)d_in[3];
  const float* W      = (const float*)d_in[4];
  const float* b      = (const float*)d_in[5];
  const float* g1     = (const float*)d_in[6];
  const float* beta1  = (const float*)d_in[7];
  const float* g2     = (const float*)d_in[8];
  const float* beta2  = (const float*)d_in[9];

  float* ws     = (float*)d_ws;
  float* P1     = ws;
  float* P2     = ws + OFF_P2;
  float* agg    = ws + OFF_AGG;
  float* stats1 = ws + OFF_STATS1;
  float* ss1    = stats1 + 256;
  float* stats2 = ss1 + 256;
  float* ss2    = stats2 + 128;
  unsigned int* hbuf = (unsigned int*)(ws + OFF_HBUF);
  float* out    = (float*)d_out;

  const bool have_hbuf = ws_size >= WS_FLOATS_NEEDED * sizeof(float);

  hipMemsetAsync(agg, 0, (size_t)N_NODES * 64 * sizeof(float), stream);
  hipMemsetAsync(stats1, 0, (256 + 256 + 128 + 128) * sizeof(float), stream);

  k_precompute<<<1024, 256, 0, stream>>>(n_feat, W, P1, P2);
  if (have_hbuf) {
    k_edge_h<<<2048, 256, 0, stream>>>(e_feat, src, dst, W, b, P1, P2, stats1, hbuf);
    k_finalize1<<<1, 128, 0, stream>>>(stats1, g1, beta1, ss1);
    k_msg_scatter<<<2048, 256, 0, stream>>>(hbuf, dst, ss1, agg);
  } else {
    k_edge_h<<<2048, 256, 0, stream>>>(e_feat, src, dst, W, b, P1, P2, stats1,
                                       (unsigned int*)(ws + OFF_AGG));  // unused-safe? no:
    // NOTE: fallback recompute path (hbuf writes above would clobber agg),
    // so in the no-hbuf case we instead run the original two-pass recompute:
    // (agg is re-zeroed below before any aggregation happens)
    hipMemsetAsync(agg, 0, (size_t)N_NODES * 64 * sizeof(float), stream);
    hipMemsetAsync(stats1, 0, (256 + 256 + 128 + 128) * sizeof(float), stream);
    k_edge_h<<<2048, 256, 0, stream>>>(e_feat, src, dst, W, b, P1, P2, stats1,
                                       (unsigned int*)(ws + OFF_AGG));
    k_finalize1<<<1, 128, 0, stream>>>(stats1, g1, beta1, ss1);
    k_edge_msg<<<2048, 256, 0, stream>>>(e_feat, src, dst, W, b, P1, P2, ss1, agg);
  }
  k_agg_stats<<<512, 256, 0, stream>>>(agg, stats2);
  k_finalize2<<<1, 64, 0, stream>>>(stats2, g2, beta2, ss2);
  k_output<<<3125, 256, 0, stream>>>(agg, n_feat, ss2, out);
}

// Round 4
// 657.642 us; speedup vs baseline: 2.6526x; 1.1922x over previous
//
#include <hip/hip_runtime.h>
#include <math.h>

// Problem constants (from reference)
#define N_NODES 50000
#define N_EDGES 800000
#define IN_DIM  192      // 2*O + ED
#define BN_EPS  1e-5f

// Workspace layout (4-byte word offsets):
//   P1p    [N,64]  uint @ 0          packed bf16x2 {chan n, chan n+64} of n_feat@W1^T
//   P2p    [N,64]  uint @ 3,200,000  same for W2^T
//   agg    [N,64]  f32  @ 6,400,000
//   stats1 [256]   f32  @ 9,600,000  (sum[128], sumsq[128])
//   ss1    [256]   f32  @ +256       (scale[128], shift[128])
//   stats2 [128]   f32  @ +512
//   ss2    [128]   f32  @ +640
//   hbuf   [E,64]  uint @ 9,601,024  packed bf16x2 {filt,core} per chan
#define OFF_P2P    3200000
#define OFF_AGG    6400000
#define OFF_STATS1 9600000
#define OFF_HBUF   9601024
#define WS_WORDS_NEEDED (OFF_HBUF + (size_t)N_EDGES * 64)

typedef __bf16 bf16x8 __attribute__((ext_vector_type(8)));
typedef __bf16 bf16x2 __attribute__((ext_vector_type(2)));
typedef float  f32x4  __attribute__((ext_vector_type(4)));

__device__ __forceinline__ unsigned pack_bf16x2(float lo, float hi) {
  union { bf16x2 v; unsigned u; } pk;
  pk.v[0] = (__bf16)lo; pk.v[1] = (__bf16)hi;
  return pk.u;
}
// fast transcendentals (native v_exp/v_log/v_rcp)
__device__ __forceinline__ float fast_sigmoid(float f) {
  return __builtin_amdgcn_rcpf(1.f + __expf(-f));
}
__device__ __forceinline__ float fast_softplus(float g) {
  return fmaxf(g, 0.f) + __logf(1.f + __expf(-fabsf(g)));
}

// ---------------------------------------------------------------------------
// Kernel 1: P1p[n][o] = pack(bf16(n_feat[n]·W[o][0:64]), bf16(n_feat[n]·W[o+64][0:64]))
//           P2p same with k-range 64:128.
// 256 threads = 64 chans (o) x 4 roles (sel): {P1 lo, P1 hi, P2 lo, P2 hi}.
__global__ __launch_bounds__(256) void k_precompute(
    const float* __restrict__ n_feat, const float* __restrict__ W,
    unsigned* __restrict__ P1p, unsigned* __restrict__ P2p) {
  const int tid = threadIdx.x;
  const int o   = tid & 63;
  const int sel = tid >> 6;                 // 0..3
  const int ch  = o + (sel & 1) * 64;
  const int kb  = (sel & 2) ? 64 : 0;
  float4 wreg[16];
  const float* wrow = W + (size_t)ch * IN_DIM + kb;
#pragma unroll
  for (int i = 0; i < 16; ++i) wreg[i] = *(const float4*)(wrow + i * 4);
  __shared__ float xrow[4][64];
  __shared__ float accbuf[4][4][64];        // [sel][r][o]
  for (int r0 = blockIdx.x * 4; r0 < N_NODES; r0 += gridDim.x * 4) {
    xrow[tid >> 6][tid & 63] = n_feat[(size_t)(r0 + (tid >> 6)) * 64 + (tid & 63)];
    __syncthreads();
    float acc[4] = {0.f, 0.f, 0.f, 0.f};
#pragma unroll
    for (int kk = 0; kk < 16; ++kk) {
      float4 wv = wreg[kk];
#pragma unroll
      for (int r = 0; r < 4; ++r) {
        float4 xv = *(const float4*)&xrow[r][kk * 4];
        acc[r] += wv.x * xv.x + wv.y * xv.y + wv.z * xv.z + wv.w * xv.w;
      }
    }
#pragma unroll
    for (int r = 0; r < 4; ++r) accbuf[sel][r][o] = acc[r];
    __syncthreads();
    // thread (o, sel) packs+writes node row r0+sel
    const size_t rr = (size_t)(r0 + sel) * 64 + o;
    P1p[rr] = pack_bf16x2(accbuf[0][sel][o], accbuf[1][sel][o]);
    P2p[rr] = pack_bf16x2(accbuf[2][sel][o], accbuf[3][sel][o]);
    __syncthreads();
  }
}

// ---------------------------------------------------------------------------
// MFMA edge-pass core.  Wave computes h[16 edges][128 ch] for group base e0.
//   Q = e_feat_tile(bf16) @ W3^T(bf16) via 16x16x32 MFMA, f32 accumulate.
//   D-frag: lane holds D[m=(lane>>4)*4+r][n=nt*16+(lane&15)]
__device__ __forceinline__ void load_W3_frags(const float* __restrict__ W,
                                              int lane, bf16x8* Bf) {
  const int c = lane & 15, q = lane >> 4;
#pragma unroll
  for (int nt = 0; nt < 8; ++nt) {
#pragma unroll
    for (int ks = 0; ks < 2; ++ks) {
      const float* wr = W + (size_t)(nt * 16 + c) * IN_DIM + 128 + ks * 32 + q * 8;
      f32x4 w0 = *(const f32x4*)wr;
      f32x4 w1 = *(const f32x4*)(wr + 4);
      bf16x8 f;
#pragma unroll
      for (int j = 0; j < 4; ++j) { f[j] = (__bf16)w0[j]; f[4 + j] = (__bf16)w1[j]; }
      Bf[nt * 2 + ks] = f;
    }
  }
}

__device__ __forceinline__ void compute_h(
    int e0, int lane, const float* __restrict__ e_feat,
    const int* __restrict__ src, const int* __restrict__ dst,
    const unsigned* __restrict__ P1p, const unsigned* __restrict__ P2p,
    const float* __restrict__ bn_, const bf16x8* Bf,
    float h[8][4], int dIdx[4]) {
  const int c = lane & 15, q = lane >> 4;
  const float* er = e_feat + (size_t)(e0 + c) * 64 + q * 8;
  f32x4 a0 = __builtin_nontemporal_load((const f32x4*)er);
  f32x4 a1 = __builtin_nontemporal_load((const f32x4*)(er + 4));
  f32x4 a2 = __builtin_nontemporal_load((const f32x4*)(er + 32));
  f32x4 a3 = __builtin_nontemporal_load((const f32x4*)(er + 36));
  int sIdx[4];
#pragma unroll
  for (int r = 0; r < 4; ++r) {
    dIdx[r] = dst[e0 + q * 4 + r];
    sIdx[r] = src[e0 + q * 4 + r];
  }
  bf16x8 A0, A1;
#pragma unroll
  for (int j = 0; j < 4; ++j) {
    A0[j] = (__bf16)a0[j]; A0[4 + j] = (__bf16)a1[j];
    A1[j] = (__bf16)a2[j]; A1[4 + j] = (__bf16)a3[j];
  }
  f32x4 acc[8];
#pragma unroll
  for (int nt = 0; nt < 8; ++nt) {
    acc[nt] = (f32x4){0.f, 0.f, 0.f, 0.f};
    acc[nt] = __builtin_amdgcn_mfma_f32_16x16x32_bf16(A0, Bf[nt * 2 + 0], acc[nt], 0, 0, 0);
    acc[nt] = __builtin_amdgcn_mfma_f32_16x16x32_bf16(A1, Bf[nt * 2 + 1], acc[nt], 0, 0, 0);
  }
  // P1/P2 packed-bf16 gathers: one dword gives chans {n, n+64}
#pragma unroll
  for (int r = 0; r < 4; ++r) {
    const unsigned* p1r = P1p + (size_t)dIdx[r] * 64 + c;
    const unsigned* p2r = P2p + (size_t)sIdx[r] * 64 + c;
#pragma unroll
    for (int ntp = 0; ntp < 4; ++ntp) {
      unsigned u1 = p1r[ntp * 16];
      unsigned u2 = p2r[ntp * 16];
      float lo = __uint_as_float(u1 << 16) + __uint_as_float(u2 << 16);
      float hi = __uint_as_float(u1 & 0xffff0000u) + __uint_as_float(u2 & 0xffff0000u);
      h[ntp][r]     = acc[ntp][r]     + lo + bn_[ntp];
      h[ntp + 4][r] = acc[ntp + 4][r] + hi + bn_[ntp + 4];
    }
  }
}

// ---------------------------------------------------------------------------
// Kernel 2: compute h, accumulate BN1 stats; if hbuf != null, also materialize
// h as packed bf16x2 {filt(chan n), core(chan n+64)} at hbuf[e*64 + n].
__global__ __launch_bounds__(256, 3) void k_edge_h(
    const float* __restrict__ e_feat, const int* __restrict__ src,
    const int* __restrict__ dst, const float* __restrict__ W,
    const float* __restrict__ b, const unsigned* __restrict__ P1p,
    const unsigned* __restrict__ P2p, float* __restrict__ stats1,
    unsigned int* __restrict__ hbuf) {
  const int tid = threadIdx.x, lane = tid & 63, w = tid >> 6;
  const int c = lane & 15, q = lane >> 4;
  bf16x8 Bf[16];
  load_W3_frags(W, lane, Bf);
  float bn_[8];
#pragma unroll
  for (int nt = 0; nt < 8; ++nt) bn_[nt] = b[nt * 16 + c];
  float sums[8] = {0, 0, 0, 0, 0, 0, 0, 0};
  float sqs[8]  = {0, 0, 0, 0, 0, 0, 0, 0};
  for (int g0 = blockIdx.x * 64; g0 < N_EDGES; g0 += gridDim.x * 64) {
    const int e0 = g0 + w * 16;
    float h[8][4]; int dIdx[4];
    compute_h(e0, lane, e_feat, src, dst, P1p, P2p, bn_, Bf, h, dIdx);
#pragma unroll
    for (int nt = 0; nt < 8; ++nt)
#pragma unroll
      for (int r = 0; r < 4; ++r) {
        sums[nt] += h[nt][r];
        sqs[nt]  += h[nt][r] * h[nt][r];
      }
    if (hbuf) {
#pragma unroll
      for (int r = 0; r < 4; ++r) {
        unsigned int* hb = hbuf + (size_t)(e0 + q * 4 + r) * 64 + c;
#pragma unroll
        for (int nt = 0; nt < 4; ++nt)
          __builtin_nontemporal_store(pack_bf16x2(h[nt][r], h[nt + 4][r]), hb + nt * 16);
      }
    }
  }
  __shared__ float red[4][256];
#pragma unroll
  for (int nt = 0; nt < 8; ++nt) {
    float s = sums[nt]; s += __shfl_xor(s, 16, 64); s += __shfl_xor(s, 32, 64);
    float qv = sqs[nt]; qv += __shfl_xor(qv, 16, 64); qv += __shfl_xor(qv, 32, 64);
    if (lane < 16) { red[w][nt * 16 + lane] = s; red[w][128 + nt * 16 + lane] = qv; }
  }
  __syncthreads();
  float v = red[0][tid] + red[1][tid] + red[2][tid] + red[3][tid];
  unsafeAtomicAdd(&stats1[tid], v);
}

// Kernel 3: fold BN1 into per-channel affine.
__global__ void k_finalize1(const float* __restrict__ stats1,
                            const float* __restrict__ g1,
                            const float* __restrict__ beta1,
                            float* __restrict__ ss1) {
  int t = threadIdx.x;
  if (t < 128) {
    float inv_n = 1.f / (float)N_EDGES;
    float mu  = stats1[t] * inv_n;
    float var = stats1[128 + t] * inv_n - mu * mu;
    float sc  = g1[t] * rsqrtf(var + BN_EPS);
    ss1[t] = sc;
    ss1[128 + t] = beta1[t] - mu * sc;
  }
}

// Kernel 4 (streaming): read packed h, BN1 affine, msg=sigmoid*softplus,
// scatter into agg[dst].  Wave per edge, lane per channel; 8-edge unroll.
__global__ __launch_bounds__(256) void k_msg_scatter(
    const unsigned int* __restrict__ hbuf, const int* __restrict__ dst,
    const float* __restrict__ ss1, float* __restrict__ agg) {
  const int tid = threadIdx.x, lane = tid & 63, w = tid >> 6;
  const float sc_f = ss1[lane], sc_g = ss1[64 + lane];
  const float sh_f = ss1[128 + lane], sh_g = ss1[192 + lane];
  const int wave_id = blockIdx.x * 4 + w;
  const int n_waves = gridDim.x * 4;
  for (int e0 = wave_id * 8; e0 < N_EDGES; e0 += n_waves * 8) {
    unsigned int p[8];
    int d[8];
#pragma unroll
    for (int j = 0; j < 8; ++j) {
      p[j] = __builtin_nontemporal_load(hbuf + (size_t)(e0 + j) * 64 + lane);
      d[j] = __builtin_amdgcn_readfirstlane(dst[e0 + j]);
    }
#pragma unroll
    for (int j = 0; j < 8; ++j) {
      float f = __uint_as_float(p[j] << 16)          * sc_f + sh_f;
      float g = __uint_as_float(p[j] & 0xffff0000u)  * sc_g + sh_g;
      unsafeAtomicAdd(&agg[(size_t)d[j] * 64 + lane], fast_sigmoid(f) * fast_softplus(g));
    }
  }
}

// Fallback pass 2 (recompute h) if ws_size is too small for hbuf.
__global__ __launch_bounds__(256, 3) void k_edge_msg(
    const float* __restrict__ e_feat, const int* __restrict__ src,
    const int* __restrict__ dst, const float* __restrict__ W,
    const float* __restrict__ b, const unsigned* __restrict__ P1p,
    const unsigned* __restrict__ P2p, const float* __restrict__ ss1,
    float* __restrict__ agg) {
  const int tid = threadIdx.x, lane = tid & 63, w = tid >> 6;
  const int c = lane & 15;
  bf16x8 Bf[16];
  load_W3_frags(W, lane, Bf);
  float bn_[8], sc[8], sh[8];
#pragma unroll
  for (int nt = 0; nt < 8; ++nt) {
    bn_[nt] = b[nt * 16 + c];
    sc[nt]  = ss1[nt * 16 + c];
    sh[nt]  = ss1[128 + nt * 16 + c];
  }
  for (int g0 = blockIdx.x * 64; g0 < N_EDGES; g0 += gridDim.x * 64) {
    const int e0 = g0 + w * 16;
    float h[8][4]; int dIdx[4];
    compute_h(e0, lane, e_feat, src, dst, P1p, P2p, bn_, Bf, h, dIdx);
#pragma unroll
    for (int nt = 0; nt < 4; ++nt) {
#pragma unroll
      for (int r = 0; r < 4; ++r) {
        float f = h[nt][r] * sc[nt] + sh[nt];
        float g = h[nt + 4][r] * sc[nt + 4] + sh[nt + 4];
        unsafeAtomicAdd(&agg[(size_t)dIdx[r] * 64 + nt * 16 + c],
                        fast_sigmoid(f) * fast_softplus(g));
      }
    }
  }
}

// Kernel 5: BN2 stats over agg rows.
__global__ __launch_bounds__(256) void k_agg_stats(const float* __restrict__ agg,
                                                   float* __restrict__ stats2) {
  const int tid = threadIdx.x;
  const int c = tid & 63, w = tid >> 6;
  float s = 0.f, sq = 0.f;
  for (int r = blockIdx.x * 4 + w; r < N_NODES; r += gridDim.x * 4) {
    float v = agg[(size_t)r * 64 + c];
    s += v; sq += v * v;
  }
  __shared__ float ws_[4][64], wq_[4][64];
  ws_[w][c] = s; wq_[w][c] = sq;
  __syncthreads();
  if (tid < 64) {
    unsafeAtomicAdd(&stats2[tid], ws_[0][tid] + ws_[1][tid] + ws_[2][tid] + ws_[3][tid]);
  } else if (tid < 128) {
    int t = tid - 64;
    unsafeAtomicAdd(&stats2[64 + t], wq_[0][t] + wq_[1][t] + wq_[2][t] + wq_[3][t]);
  }
}

__global__ void k_finalize2(const float* __restrict__ stats2,
                            const float* __restrict__ g2,
                            const float* __restrict__ beta2,
                            float* __restrict__ ss2) {
  int t = threadIdx.x;
  if (t < 64) {
    float inv_n = 1.f / (float)N_NODES;
    float mu  = stats2[t] * inv_n;
    float var = stats2[64 + t] * inv_n - mu * mu;
    float sc  = g2[t] * rsqrtf(var + BN_EPS);
    ss2[t] = sc;
    ss2[64 + t] = beta2[t] - mu * sc;
  }
}

// Kernel 7: out = softplus(BN2(agg) + n_feat), float4-vectorized.
__global__ __launch_bounds__(256) void k_output(const float* __restrict__ agg,
                                                const float* __restrict__ n_feat,
                                                const float* __restrict__ ss2,
                                                float* __restrict__ out) {
  int i = blockIdx.x * 256 + threadIdx.x;
  if (i >= N_NODES * 16) return;
  int cb = (i & 15) * 4;
  float4 a = ((const float4*)agg)[i];
  float4 x = ((const float4*)n_feat)[i];
  float4 r;
  r.x = fast_softplus(a.x * ss2[cb + 0] + ss2[64 + cb + 0] + x.x);
  r.y = fast_softplus(a.y * ss2[cb + 1] + ss2[64 + cb + 1] + x.y);
  r.z = fast_softplus(a.z * ss2[cb + 2] + ss2[64 + cb + 2] + x.z);
  r.w = fast_softplus(a.w * ss2[cb + 3] + ss2[64 + cb + 3] + x.w);
  ((float4*)out)[i] = r;
}

extern "C" void kernel_launch(void* const* d_in, const int* in_sizes, int n_in,
                              void* d_out, int out_size, void* d_ws, size_t ws_size,
                              hipStream_t stream) {
  const float* n_feat = (const float*)d_in[0];
  const float* e_feat = (const float*)d_in[1];
  const int*   src    = (const int*)d_in[2];
  const int*   dst    = (const int*)d_in[3];
  const float* W      = (const float*)d_in[4];
  const float* b      = (const float*)d_in[5];
  const float* g1     = (const float*)d_in[6];
  const float* beta1  = (const float*)d_in[7];
  const float* g2     = (const float*)d_in[8];
  const float* beta2  = (const float*)d_in[9];

  unsigned* ws  = (unsigned*)d_ws;
  unsigned* P1p = ws;
  unsigned* P2p = ws + OFF_P2P;
  float* agg    = (float*)(ws + OFF_AGG);
  float* stats1 = (float*)(ws + OFF_STATS1);
  float* ss1    = stats1 + 256;
  float* stats2 = ss1 + 256;
  float* ss2    = stats2 + 128;
  unsigned int* hbuf = ws + OFF_HBUF;
  float* out    = (float*)d_out;

  const bool have_hbuf = ws_size >= WS_WORDS_NEEDED * 4;

  hipMemsetAsync(agg, 0, (size_t)N_NODES * 64 * sizeof(float), stream);
  hipMemsetAsync(stats1, 0, (256 + 256 + 128 + 128) * sizeof(float), stream);

  k_precompute<<<1024, 256, 0, stream>>>(n_feat, W, P1p, P2p);
  if (have_hbuf) {
    k_edge_h<<<2048, 256, 0, stream>>>(e_feat, src, dst, W, b, P1p, P2p, stats1, hbuf);
    k_finalize1<<<1, 128, 0, stream>>>(stats1, g1, beta1, ss1);
    k_msg_scatter<<<2048, 256, 0, stream>>>(hbuf, dst, ss1, agg);
  } else {
    k_edge_h<<<2048, 256, 0, stream>>>(e_feat, src, dst, W, b, P1p, P2p, stats1, nullptr);
    k_finalize1<<<1, 128, 0, stream>>>(stats1, g1, beta1, ss1);
    k_edge_msg<<<2048, 256, 0, stream>>>(e_feat, src, dst, W, b, P1p, P2p, ss1, agg);
  }
  k_agg_stats<<<512, 256, 0, stream>>>(agg, stats2);
  k_finalize2<<<1, 64, 0, stream>>>(stats2, g2, beta2, ss2);
  k_output<<<3125, 256, 0, stream>>>(agg, n_feat, ss2, out);
}